// Round 17
// baseline (327.827 us; speedup 1.0000x reference)
//
#include <hip/hip_runtime.h>

#define MT 45012
#define NTOT 11253
#define BB 4

typedef __attribute__((ext_vector_type(8))) __bf16 bf16x8;
typedef __attribute__((ext_vector_type(4))) float f32x4;

__device__ __forceinline__ unsigned short f2bf(float f) {
  unsigned u = __float_as_uint(f);
  u += 0x7FFFu + ((u >> 16) & 1u);
  return (unsigned short)(u >> 16);
}

__device__ __forceinline__ float bf2f(unsigned short v) {
  return __uint_as_float((unsigned)v << 16);
}

__device__ __forceinline__ void gld16(const unsigned short* g, unsigned short* l) {
  __builtin_amdgcn_global_load_lds((const __attribute__((address_space(1))) unsigned int*)g,
                                   (__attribute__((address_space(3))) unsigned int*)l, 16, 0, 0);
}

// ---------------- unified weight prep ----------------
__global__ __launch_bounds__(256) void prep_kernel(const float* __restrict__ Wv, const float* __restrict__ Wo,
                                                   const float* __restrict__ Wa, const float* __restrict__ Wu,
                                                   const float* __restrict__ W1, const float* __restrict__ W2,
                                                   const float* __restrict__ boff, const float* __restrict__ battn,
                                                   unsigned short* __restrict__ Tv, unsigned short* __restrict__ Toa,
                                                   unsigned short* __restrict__ Tu,
                                                   unsigned short* __restrict__ T1, unsigned short* __restrict__ T2,
                                                   float* __restrict__ c_oa, float* __restrict__ b_oa) {
  int bid = blockIdx.x, t = threadIdx.x;
  if (bid < 256) {
    int n = bid, k = t;
    Tv[n * 256 + k] = f2bf(Wv[(size_t)k * 256 + n]);
  } else if (bid < 640) {
    int n = bid - 256, k = t;
    float v = (n < 256) ? Wo[(size_t)k * 256 + n] : Wa[(size_t)k * 128 + (n - 256)];
    Toa[n * 256 + k] = f2bf(v);
  } else if (bid < 896) {
    int n = bid - 640, k = t;
    Tu[n * 256 + k] = f2bf(Wu[(size_t)k * 256 + n]);
  } else if (bid < 1920) {
    int i = (bid - 896) * 256 + t;
    int n = i / 256, k = i % 256;
    T1[i] = f2bf(W1[(size_t)k * 1024 + n]);
  } else if (bid < 2944) {
    int i = (bid - 1920) * 256 + t;
    int n = i / 1024, k = i % 1024;
    T2[i] = f2bf(W2[(size_t)k * 256 + n]);
  } else {
    int i = (bid - 2944) * 256 + t;
    if (i < 256) { c_oa[i] = Wo[256 * 256 + i]; b_oa[i] = boff[i]; }
    else if (i < 384) { c_oa[i] = Wa[256 * 128 + (i - 256)]; b_oa[i] = battn[i - 256]; }
  }
}

// ---------------- activation convert: src_bf16, qa = bf16(src+pos) ----------------
__global__ __launch_bounds__(256) void cvt_kernel(const float4* __restrict__ src4,
                                                  const float4* __restrict__ pos4,
                                                  ushort4* __restrict__ sb,
                                                  ushort4* __restrict__ qb) {
  int i = blockIdx.x * 256 + threadIdx.x;
  if (i >= MT * 64) return;
  float4 s = src4[i], p = pos4[i];
  sb[i] = make_ushort4(f2bf(s.x), f2bf(s.y), f2bf(s.z), f2bf(s.w));
  qb[i] = make_ushort4(f2bf(s.x + p.x), f2bf(s.y + p.y), f2bf(s.z + p.z), f2bf(s.w + p.w));
}

// ---------------- per (b,level) corr-softmax stats ----------------
__global__ __launch_bounds__(256) void stats_kernel(const float* __restrict__ c0,
                                                    const float* __restrict__ c1,
                                                    const float* __restrict__ c2,
                                                    const float* __restrict__ c3,
                                                    const float* __restrict__ vr,
                                                    float* __restrict__ stats) {
  const int LS[4] = {92, 46, 23, 12};
  const int LHW[4] = {8464, 2116, 529, 144};
  int b = blockIdx.x >> 2, l = blockIdx.x & 3;
  const float* cp = (l == 0) ? c0 : (l == 1) ? c1 : (l == 2) ? c2 : c3;
  int S = LS[l], HW = LHW[l];
  float vrx = vr[(b * 4 + l) * 2 + 0], vry = vr[(b * 4 + l) * 2 + 1];
  int tid = threadIdx.x;
  __shared__ float red[4];

  float mx = -INFINITY;
  for (int i = tid; i < HW; i += 256) {
    float c = cp[(size_t)b * HW + i];
    if (c >= 0.5f) mx = fmaxf(mx, c);
  }
  for (int o = 32; o; o >>= 1) mx = fmaxf(mx, __shfl_xor(mx, o));
  if ((tid & 63) == 0) red[tid >> 6] = mx;
  __syncthreads();
  mx = fmaxf(fmaxf(red[0], red[1]), fmaxf(red[2], red[3]));
  float mx_eff = isinf(mx) ? 0.f : mx;
  __syncthreads();

  float den = 0.f, cx = 0.f, cy = 0.f;
  float invW = 1.f / (vrx * (float)S), invH = 1.f / (vry * (float)S);
  for (int i = tid; i < HW; i += 256) {
    float c = cp[(size_t)b * HW + i];
    if (c >= 0.5f) {
      float e = expf(c - mx_eff);
      int x = i % S, y = i / S;
      den += e;
      cx += e * ((float)x + 0.5f) * invW;
      cy += e * ((float)y + 0.5f) * invH;
    }
  }
  float vals[3] = {den, cx, cy};
  for (int j = 0; j < 3; ++j) {
    float v = vals[j];
    for (int o = 32; o; o >>= 1) v += __shfl_xor(v, o);
    if ((tid & 63) == 0) red[tid >> 6] = v;
    __syncthreads();
    v = red[0] + red[1] + red[2] + red[3];
    vals[j] = v;
    __syncthreads();
  }
  if (tid == 0) {
    float* s = stats + (size_t)(b * 4 + l) * 4;
    s[0] = mx_eff; s[1] = vals[0]; s[2] = vals[1]; s[3] = vals[2];
  }
}

// ---------------- reference points + corr_all ----------------
__global__ __launch_bounds__(256) void refpt_kernel(const float* __restrict__ c0,
                                                    const float* __restrict__ c1,
                                                    const float* __restrict__ c2,
                                                    const float* __restrict__ c3,
                                                    const float* __restrict__ vr,
                                                    const float* __restrict__ stats,
                                                    float* __restrict__ refpt,
                                                    float* __restrict__ corr_all) {
  int i = blockIdx.x * 256 + threadIdx.x;
  if (i >= MT) return;
  int b = i / NTOT, n = i % NTOT;
  int l = (n < 8464) ? 0 : (n < 10580) ? 1 : (n < 11109) ? 2 : 3;
  const int LS[4] = {92, 46, 23, 12};
  const int LSTART[4] = {0, 8464, 10580, 11109};
  const int LHW[4] = {8464, 2116, 529, 144};
  int S = LS[l], start = LSTART[l], HW = LHW[l];
  int local = n - start;
  int x = local % S, y = local / S;
  float vrx = vr[(b * 4 + l) * 2 + 0], vry = vr[(b * 4 + l) * 2 + 1];
  float rx = ((float)x + 0.5f) / (vrx * (float)S);
  float ry = ((float)y + 0.5f) / (vry * (float)S);
  const float* cp = (l == 0) ? c0 : (l == 1) ? c1 : (l == 2) ? c2 : c3;
  float c = cp[(size_t)b * HW + local];
  const float* st = stats + (size_t)(b * 4 + l) * 4;
  float mx = st[0], den = st[1], cxs = st[2], cys = st[3];
  float sm = 0.f, cenx = 0.f, ceny = 0.f;
  if (den > 0.f) {
    if (c >= 0.5f) sm = expf(c - mx) / fmaxf(den, 1e-30f);
    cenx = cxs / den; ceny = cys / den;
  }
  float dx = fminf(fmaxf(cenx - rx, -0.5f), 0.5f) * sm;
  float dy = fminf(fmaxf(ceny - ry, -0.5f), 0.5f) * sm;
  refpt[2 * i] = rx + dx;
  refpt[2 * i + 1] = ry + dy;
  corr_all[i] = c;
}

// ======= round-8 gemmS core (validated): 128x128 tile, BK=64, single-buffer, XOR swizzle =======
#define GEMM_CORE(A_, Bt_, K_)                                                         \
  const int tid = threadIdx.x;                                                         \
  const int wid = tid >> 6, lane = tid & 63;                                           \
  const int row0 = blockIdx.x * 128;                                                   \
  const int wm = wid >> 1, wn = wid & 1;                                               \
  const int l15 = lane & 15;                                                           \
  const int hi = lane >> 4;                                                            \
  const int s7 = l15 & 7;                                                              \
  __shared__ __align__(16) unsigned short Als[128][64];                                \
  __shared__ __align__(16) unsigned short Bls[128][64];                                \
  f32x4 acc[4][4];                                                                     \
  const f32x4 zero = {0.f, 0.f, 0.f, 0.f};                                             \
  _Pragma("unroll") for (int a = 0; a < 4; ++a)                                        \
    _Pragma("unroll") for (int c = 0; c < 4; ++c) acc[a][c] = zero;                    \
  const unsigned short* gA[4];                                                         \
  const unsigned short* gB[4];                                                         \
  unsigned short* lA[4];                                                               \
  unsigned short* lB[4];                                                               \
  _Pragma("unroll") for (int j = 0; j < 4; ++j) {                                      \
    int cch = tid + 256 * j;                                                           \
    int rrow = cch >> 3;                                                               \
    int gseg = (cch & 7) ^ (rrow & 7);                                                 \
    int ra = row0 + rrow; if (ra > MT - 1) ra = MT - 1;                                \
    gA[j] = A_ + (size_t)ra * K_ + gseg * 8;                                           \
    gB[j] = Bt_ + (size_t)(col0 + rrow) * K_ + gseg * 8;                               \
    lA[j] = &Als[0][0] + (size_t)cch * 8;                                              \
    lB[j] = &Bls[0][0] + (size_t)cch * 8;                                              \
  }                                                                                    \
  for (int k0 = 0; k0 < K_; k0 += 64) {                                                \
    __syncthreads();                                                                   \
    _Pragma("unroll") for (int j = 0; j < 4; ++j) gld16(gA[j] + k0, lA[j]);            \
    _Pragma("unroll") for (int j = 0; j < 4; ++j) gld16(gB[j] + k0, lB[j]);            \
    __syncthreads();                                                                   \
    _Pragma("unroll") for (int ks = 0; ks < 2; ++ks) {                                 \
      bf16x8 av[4], bv[4];                                                             \
      const int m = ks * 4 + hi;                                                       \
      _Pragma("unroll") for (int f = 0; f < 4; ++f) {                                  \
        av[f] = *(const bf16x8*)&Als[wm * 64 + f * 16 + l15][(m ^ s7) * 8];            \
        bv[f] = *(const bf16x8*)&Bls[wn * 64 + f * 16 + l15][(m ^ s7) * 8];            \
      }                                                                                \
      _Pragma("unroll") for (int fm = 0; fm < 4; ++fm)                                 \
        _Pragma("unroll") for (int fn = 0; fn < 4; ++fn)                               \
          acc[fm][fn] = __builtin_amdgcn_mfma_f32_16x16x32_bf16(av[fm], bv[fn], acc[fm][fn], 0, 0, 0); \
    }                                                                                  \
  }

// ---------------- gemmS: EPI 3 = bf16 relu out (FFN1) ----------------
template <int EPI>
__global__ __launch_bounds__(256, 3) void gemmS(const unsigned short* __restrict__ A,
                                                const unsigned short* __restrict__ Bt,
                                                const float* __restrict__ bias,
                                                void* __restrict__ out,
                                                int K, int N) {
  const int col0 = blockIdx.y * 128;
  GEMM_CORE(A, Bt, K)
#pragma unroll
  for (int fm = 0; fm < 4; ++fm) {
#pragma unroll
    for (int fn = 0; fn < 4; ++fn) {
      int gcol = col0 + wn * 64 + fn * 16 + l15;
      float bcol = bias[gcol];
#pragma unroll
      for (int r = 0; r < 4; ++r) {
        int grow = row0 + wm * 64 + fm * 16 + hi * 4 + r;
        if (grow < MT) {
          float v = acc[fm][fn][r] + bcol;
          ((unsigned short*)out)[(size_t)grow * N + gcol] = f2bf(fmaxf(v, 0.f));
        }
      }
    }
  }
}

// ---------------- merged value + offsets/logits GEMM (both K=256, all bf16 out) ----------------
__global__ __launch_bounds__(256, 3) void gemm_voa(const unsigned short* __restrict__ Av,
                                                   const unsigned short* __restrict__ Aoa,
                                                   const unsigned short* __restrict__ Btv,
                                                   const unsigned short* __restrict__ Btoa,
                                                   const float* __restrict__ bv,
                                                   const float* __restrict__ boa,
                                                   const float* __restrict__ c_oa,
                                                   const float* __restrict__ corr,
                                                   unsigned short* __restrict__ outv,
                                                   unsigned short* __restrict__ outo,
                                                   unsigned short* __restrict__ outl) {
  const bool isV = blockIdx.y < 2;
  const int col0 = (isV ? blockIdx.y : blockIdx.y - 2) * 128;
  const unsigned short* A = isV ? Av : Aoa;
  const unsigned short* Bt = isV ? Btv : Btoa;
  const float* bias = isV ? bv : boa;
  GEMM_CORE(A, Bt, 256)
#pragma unroll
  for (int fm = 0; fm < 4; ++fm) {
#pragma unroll
    for (int fn = 0; fn < 4; ++fn) {
      int gcol = col0 + wn * 64 + fn * 16 + l15;
      float bcol = bias[gcol];
      float cv = isV ? 0.f : c_oa[gcol];
#pragma unroll
      for (int r = 0; r < 4; ++r) {
        int grow = row0 + wm * 64 + fm * 16 + hi * 4 + r;
        if (grow < MT) {
          float v = acc[fm][fn][r] + bcol;
          if (isV) {
            outv[(size_t)grow * 256 + gcol] = f2bf(v);
          } else {
            v += corr[grow] * cv;
            if (gcol < 256) outo[(size_t)grow * 256 + gcol] = f2bf(v);
            else outl[(size_t)grow * 128 + gcol - 256] = f2bf(v);
          }
        }
      }
    }
  }
}

// ---------------- fused GEMM + bf16 residual + LayerNorm: 64x256 tile (full rows) ----------------
// out = LN(A @ Bt^T + bias + resid) * g + b ; OUTF32: 1 -> f32 (d_out), 0 -> bf16
template <int OUTF32>
__global__ __launch_bounds__(256, 3) void gemm_ln(const unsigned short* __restrict__ A,
                                                  const unsigned short* __restrict__ Bt,
                                                  const float* __restrict__ bias,
                                                  const unsigned short* __restrict__ residbf,
                                                  const float* __restrict__ lng,
                                                  const float* __restrict__ lnb,
                                                  void* __restrict__ out,
                                                  int K) {
  const int tid = threadIdx.x;
  const int w = tid >> 6, lane = tid & 63;
  const int row0 = blockIdx.x * 64;
  const int l15 = lane & 15;
  const int hi = lane >> 4;
  const int s7 = l15 & 7;

  __shared__ __align__(16) unsigned short Als[64][64];
  __shared__ __align__(16) unsigned short Bls[256][64];

  f32x4 acc[16];
  const f32x4 zero = {0.f, 0.f, 0.f, 0.f};
#pragma unroll
  for (int cf = 0; cf < 16; ++cf) acc[cf] = zero;

  // A staging: chunks c = tid + 256j (j=0..1); B staging: chunks tid + 256j (j=0..7)
  const unsigned short* gA[2];
  unsigned short* lA[2];
#pragma unroll
  for (int j = 0; j < 2; ++j) {
    int c = tid + 256 * j;
    int rrow = c >> 3;
    int gseg = (c & 7) ^ (rrow & 7);
    int ra = row0 + rrow; if (ra > MT - 1) ra = MT - 1;
    gA[j] = A + (size_t)ra * K + gseg * 8;
    lA[j] = &Als[0][0] + (size_t)c * 8;
  }
  const unsigned short* gB[8];
  unsigned short* lB[8];
#pragma unroll
  for (int j = 0; j < 8; ++j) {
    int c = tid + 256 * j;
    int rrow = c >> 3;
    int gseg = (c & 7) ^ (rrow & 7);
    gB[j] = Bt + (size_t)rrow * K + gseg * 8;
    lB[j] = &Bls[0][0] + (size_t)c * 8;
  }

  for (int k0 = 0; k0 < K; k0 += 64) {
    __syncthreads();
#pragma unroll
    for (int j = 0; j < 2; ++j) gld16(gA[j] + k0, lA[j]);
#pragma unroll
    for (int j = 0; j < 8; ++j) gld16(gB[j] + k0, lB[j]);
    __syncthreads();
#pragma unroll
    for (int ks = 0; ks < 2; ++ks) {
      const int m = ks * 4 + hi;
      bf16x8 av = *(const bf16x8*)&Als[w * 16 + l15][(m ^ s7) * 8];
#pragma unroll
      for (int cf = 0; cf < 16; ++cf) {
        bf16x8 bvv = *(const bf16x8*)&Bls[cf * 16 + l15][(m ^ s7) * 8];
        acc[cf] = __builtin_amdgcn_mfma_f32_16x16x32_bf16(av, bvv, acc[cf], 0, 0, 0);
      }
    }
  }

  // ---- epilogue: per output row, add bias+resid, LayerNorm across 256 cols ----
#pragma unroll
  for (int r = 0; r < 4; ++r) {
    int grow = row0 + w * 16 + hi * 4 + r;
    bool valid = grow < MT;
    float vals[16];
    float s = 0.f;
#pragma unroll
    for (int cf = 0; cf < 16; ++cf) {
      int gcol = cf * 16 + l15;
      float v = acc[cf][r] + bias[gcol];
      if (valid) v += bf2f(residbf[(size_t)grow * 256 + gcol]);
      vals[cf] = v;
      s += v;
    }
    for (int o = 1; o < 16; o <<= 1) s += __shfl_xor(s, o);
    float mean = s * (1.f / 256.f);
    float q = 0.f;
#pragma unroll
    for (int cf = 0; cf < 16; ++cf) {
      float d = vals[cf] - mean;
      q += d * d;
    }
    for (int o = 1; o < 16; o <<= 1) q += __shfl_xor(q, o);
    float rstd = rsqrtf(q * (1.f / 256.f) + 1e-5f);
    if (valid) {
#pragma unroll
      for (int cf = 0; cf < 16; ++cf) {
        int gcol = cf * 16 + l15;
        float o = (vals[cf] - mean) * rstd * lng[gcol] + lnb[gcol];
        if constexpr (OUTF32) {
          ((float*)out)[(size_t)grow * 256 + gcol] = o;
        } else {
          ((unsigned short*)out)[(size_t)grow * 256 + gcol] = f2bf(o);
        }
      }
    }
  }
}

// ---------------- deformable sampling (R14-validated: bf16 value/offs/logits, fused softmax) ----------------
__global__ __launch_bounds__(256) void sampler2_kernel(const unsigned short* __restrict__ value,
                                                       const unsigned* __restrict__ offs_bf,
                                                       const unsigned short* __restrict__ logits_bf,
                                                       const float* __restrict__ refpt,
                                                       const float* __restrict__ vr,
                                                       unsigned short* __restrict__ outs) {
  const int LS[4] = {92, 46, 23, 12};
  const int LSTART[4] = {0, 8464, 10580, 11109};
  const int tid = threadIdx.x;
  const int rsel = tid >> 7;
  const int r = blockIdx.x * 2 + rsel;

  __shared__ __align__(16) int4 s_addr[2][8][17];
  __shared__ __align__(16) float4 s_w[2][8][17];

  // ---- phase 1: one thread per (h,l,p) point ----
  {
    int pt = tid & 127;
    int l = (pt >> 2) & 3;
    int h = pt >> 4;
    int b = r / NTOT;
    unsigned op = offs_bf[(size_t)r * 128 + pt];
    float ox = __uint_as_float(op << 16);
    float oy = __uint_as_float(op & 0xFFFF0000u);
    float lg = bf2f(logits_bf[(size_t)r * 128 + pt]);
    float m = lg;
    for (int o = 1; o < 16; o <<= 1) m = fmaxf(m, __shfl_xor(m, o));
    float e = expf(lg - m);
    float s = e;
    for (int o = 1; o < 16; o <<= 1) s += __shfl_xor(s, o);
    float aw = e / s;

    float rx = refpt[2 * r], ry = refpt[2 * r + 1];
    float vrx = vr[(b * 4 + l) * 2 + 0], vry = vr[(b * 4 + l) * 2 + 1];
    int S = LS[l];
    float fS = (float)S;
    float xf = rx * vrx * fS + ox - 0.5f;
    float yf = ry * vry * fS + oy - 0.5f;
    float x0f = floorf(xf), y0f = floorf(yf);
    float wx = xf - x0f, wy = yf - y0f;
    int x0 = (int)x0f, y0 = (int)y0f;
    int x1 = x0 + 1, y1 = y0 + 1;
    float vx0 = ((unsigned)x0 < (unsigned)S) ? 1.f : 0.f;
    float vx1 = ((unsigned)x1 < (unsigned)S) ? 1.f : 0.f;
    float vy0 = ((unsigned)y0 < (unsigned)S) ? 1.f : 0.f;
    float vy1 = ((unsigned)y1 < (unsigned)S) ? 1.f : 0.f;
    int cx0 = min(max(x0, 0), S - 1), cx1 = min(max(x1, 0), S - 1);
    int cy0 = min(max(y0, 0), S - 1), cy1 = min(max(y1, 0), S - 1);
    int base = (b * NTOT + LSTART[l]) * 512 + h * 64;
    int4 a;
    a.x = base + (cy0 * S + cx0) * 512;
    a.y = base + (cy0 * S + cx1) * 512;
    a.z = base + (cy1 * S + cx0) * 512;
    a.w = base + (cy1 * S + cx1) * 512;
    float iwx = 1.f - wx, iwy = 1.f - wy;
    float4 w;
    w.x = aw * iwx * iwy * vx0 * vy0;
    w.y = aw * wx * iwy * vx1 * vy0;
    w.z = aw * iwx * wy * vx0 * vy1;
    w.w = aw * wx * wy * vx1 * vy1;
    s_addr[rsel][h][pt & 15] = a;
    s_w[rsel][h][pt & 15] = w;
  }
  __syncthreads();

  // ---- phase 2: (h, chpair) accumulate over 16 points ----
  const int h = (tid >> 4) & 7, cp = tid & 15;
  const char* vb = (const char*)value;
  const int cpo = cp * 4;
  float a0 = 0.f, a1 = 0.f;
#pragma unroll 4
  for (int i = 0; i < 16; ++i) {
    int4 a = s_addr[rsel][h][i];
    float4 w = s_w[rsel][h][i];
    unsigned u00 = *(const unsigned*)(vb + (size_t)(unsigned)(a.x + cpo));
    unsigned u01 = *(const unsigned*)(vb + (size_t)(unsigned)(a.y + cpo));
    unsigned u10 = *(const unsigned*)(vb + (size_t)(unsigned)(a.z + cpo));
    unsigned u11 = *(const unsigned*)(vb + (size_t)(unsigned)(a.w + cpo));
    float f00l = __uint_as_float(u00 << 16), f00h = __uint_as_float(u00 & 0xFFFF0000u);
    float f01l = __uint_as_float(u01 << 16), f01h = __uint_as_float(u01 & 0xFFFF0000u);
    float f10l = __uint_as_float(u10 << 16), f10h = __uint_as_float(u10 & 0xFFFF0000u);
    float f11l = __uint_as_float(u11 << 16), f11h = __uint_as_float(u11 & 0xFFFF0000u);
    a0 += w.x * f00l + w.y * f01l + w.z * f10l + w.w * f11l;
    a1 += w.x * f00h + w.y * f01h + w.z * f10h + w.w * f11h;
  }
  unsigned packed = (unsigned)f2bf(a0) | ((unsigned)f2bf(a1) << 16);
  ((unsigned*)outs)[(size_t)r * 128 + h * 16 + cp] = packed;
}

// ---------------- launch ----------------
extern "C" void kernel_launch(void* const* d_in, const int* in_sizes, int n_in,
                              void* d_out, int out_size, void* d_ws, size_t ws_size,
                              hipStream_t stream) {
  (void)in_sizes; (void)n_in; (void)out_size; (void)ws_size;
  const float* src = (const float*)d_in[0];
  const float* pos = (const float*)d_in[1];
  const float* c0 = (const float*)d_in[2];
  const float* c1 = (const float*)d_in[3];
  const float* c2 = (const float*)d_in[4];
  const float* c3 = (const float*)d_in[5];
  const float* vr = (const float*)d_in[6];
  const float* W_off = (const float*)d_in[8];
  const float* b_off = (const float*)d_in[9];
  const float* W_attn = (const float*)d_in[10];
  const float* b_attn = (const float*)d_in[11];
  const float* W_val = (const float*)d_in[12];
  const float* b_val = (const float*)d_in[13];
  const float* W_out = (const float*)d_in[14];
  const float* b_out = (const float*)d_in[15];
  const float* ln1g = (const float*)d_in[16];
  const float* ln1b = (const float*)d_in[17];
  const float* W1 = (const float*)d_in[18];
  const float* b1 = (const float*)d_in[19];
  const float* W2 = (const float*)d_in[20];
  const float* b2 = (const float*)d_in[21];
  const float* ln2g = (const float*)d_in[22];
  const float* ln2b = (const float*)d_in[23];

  char* ws = (char*)d_ws;
  // S1 (46MB): value_bf16 (23MB)
  unsigned short* value_bf = (unsigned short*)(ws + 0);
  // S2 (46MB): offs_bf (23MB, then x_bf16 overwrites) + logits_bf (11.5MB)
  unsigned* offs_bf = (unsigned*)(ws + 46092288);
  unsigned short* x_bf16 = (unsigned short*)(ws + 46092288);
  unsigned short* logits_bf = (unsigned short*)(ws + 69138432);
  // S4 (23MB): src_bf16 (persists through outproj as residual)
  unsigned short* src_bf16 = (unsigned short*)(ws + 92184576);
  // region C (92MB): qa (front 23MB) -> out_s -> hbuf spans all
  unsigned short* qa = (unsigned short*)(ws + 115230720);
  unsigned short* out_s = qa;
  unsigned short* hbuf = (unsigned short*)(ws + 115230720);
  // small region
  unsigned short* Wt_val = (unsigned short*)(ws + 207415296);
  unsigned short* Wt_oa = (unsigned short*)(ws + 207546368);
  unsigned short* Wt_out = (unsigned short*)(ws + 207742976);
  unsigned short* Wt1 = (unsigned short*)(ws + 207874048);
  unsigned short* Wt2 = (unsigned short*)(ws + 208398336);
  float* c_oa = (float*)(ws + 208922624);
  float* refpt = (float*)(ws + 208924160);
  float* corr_all = (float*)(ws + 209284256);
  float* stats = (float*)(ws + 209464304);
  float* b_oa = (float*)(ws + 209465344);

  prep_kernel<<<2946, 256, 0, stream>>>(W_val, W_off, W_attn, W_out, W1, W2, b_off, b_attn,
                                        Wt_val, Wt_oa, Wt_out, Wt1, Wt2, c_oa, b_oa);

  cvt_kernel<<<11253, 256, 0, stream>>>((const float4*)src, (const float4*)pos,
                                        (ushort4*)src_bf16, (ushort4*)qa);
  stats_kernel<<<16, 256, 0, stream>>>(c0, c1, c2, c3, vr, stats);
  refpt_kernel<<<176, 256, 0, stream>>>(c0, c1, c2, c3, vr, stats, refpt, corr_all);

  dim3 blk(256);
  // merged: value bf16 (y<2) + offsets/logits bf16 (y>=2)
  gemm_voa<<<dim3(352, 5), blk, 0, stream>>>(src_bf16, qa, Wt_val, Wt_oa, b_val, b_oa,
                                             c_oa, corr_all, value_bf,
                                             (unsigned short*)offs_bf, logits_bf);
  // deformable sampling -> out_s (bf16, in qa slot; src_bf16 preserved)
  sampler2_kernel<<<MT / 2, 256, 0, stream>>>(value_bf, offs_bf, logits_bf, refpt, vr, out_s);
  // fused outproj + resid(src) + LN1 -> x_bf16 (overwrites offs_bf, dead)
  gemm_ln<0><<<704, blk, 0, stream>>>(out_s, Wt_out, b_out, src_bf16, ln1g, ln1b, x_bf16, 256);
  // FFN1: h = bf16(relu(x @ W1 + b1))
  gemmS<3><<<dim3(352, 8), blk, 0, stream>>>(x_bf16, Wt1, b1, hbuf, 256, 1024);
  // fused FFN2 + resid(x) + LN2 -> d_out (f32)
  gemm_ln<1><<<704, blk, 0, stream>>>(hbuf, Wt2, b2, x_bf16, ln2g, ln2b, d_out, 1024);
}

// Round 18
// 316.933 us; speedup vs baseline: 1.0344x; 1.0344x over previous
//
#include <hip/hip_runtime.h>

#define MT 45012
#define NTOT 11253
#define BB 4

typedef __attribute__((ext_vector_type(8))) __bf16 bf16x8;
typedef __attribute__((ext_vector_type(4))) float f32x4;

__device__ __forceinline__ unsigned short f2bf(float f) {
  unsigned u = __float_as_uint(f);
  u += 0x7FFFu + ((u >> 16) & 1u);
  return (unsigned short)(u >> 16);
}

__device__ __forceinline__ float bf2f(unsigned short v) {
  return __uint_as_float((unsigned)v << 16);
}

__device__ __forceinline__ void gld16(const unsigned short* g, unsigned short* l) {
  __builtin_amdgcn_global_load_lds((const __attribute__((address_space(1))) unsigned int*)g,
                                   (__attribute__((address_space(3))) unsigned int*)l, 16, 0, 0);
}

// ---------------- unified weight prep ----------------
__global__ __launch_bounds__(256) void prep_kernel(const float* __restrict__ Wv, const float* __restrict__ Wo,
                                                   const float* __restrict__ Wa, const float* __restrict__ Wu,
                                                   const float* __restrict__ W1, const float* __restrict__ W2,
                                                   const float* __restrict__ boff, const float* __restrict__ battn,
                                                   unsigned short* __restrict__ Tv, unsigned short* __restrict__ Toa,
                                                   unsigned short* __restrict__ Tu,
                                                   unsigned short* __restrict__ T1, unsigned short* __restrict__ T2,
                                                   float* __restrict__ c_oa, float* __restrict__ b_oa) {
  int bid = blockIdx.x, t = threadIdx.x;
  if (bid < 256) {
    int n = bid, k = t;
    Tv[n * 256 + k] = f2bf(Wv[(size_t)k * 256 + n]);
  } else if (bid < 640) {
    int n = bid - 256, k = t;
    float v = (n < 256) ? Wo[(size_t)k * 256 + n] : Wa[(size_t)k * 128 + (n - 256)];
    Toa[n * 256 + k] = f2bf(v);
  } else if (bid < 896) {
    int n = bid - 640, k = t;
    Tu[n * 256 + k] = f2bf(Wu[(size_t)k * 256 + n]);
  } else if (bid < 1920) {
    int i = (bid - 896) * 256 + t;
    int n = i / 256, k = i % 256;
    T1[i] = f2bf(W1[(size_t)k * 1024 + n]);
  } else if (bid < 2944) {
    int i = (bid - 1920) * 256 + t;
    int n = i / 1024, k = i % 1024;
    T2[i] = f2bf(W2[(size_t)k * 256 + n]);
  } else {
    int i = (bid - 2944) * 256 + t;
    if (i < 256) { c_oa[i] = Wo[256 * 256 + i]; b_oa[i] = boff[i]; }
    else if (i < 384) { c_oa[i] = Wa[256 * 128 + (i - 256)]; b_oa[i] = battn[i - 256]; }
  }
}

// ---------------- activation convert: src_bf16, qa = bf16(src+pos) ----------------
__global__ __launch_bounds__(256) void cvt_kernel(const float4* __restrict__ src4,
                                                  const float4* __restrict__ pos4,
                                                  ushort4* __restrict__ sb,
                                                  ushort4* __restrict__ qb) {
  int i = blockIdx.x * 256 + threadIdx.x;
  if (i >= MT * 64) return;
  float4 s = src4[i], p = pos4[i];
  sb[i] = make_ushort4(f2bf(s.x), f2bf(s.y), f2bf(s.z), f2bf(s.w));
  qb[i] = make_ushort4(f2bf(s.x + p.x), f2bf(s.y + p.y), f2bf(s.z + p.z), f2bf(s.w + p.w));
}

// ---------------- per (b,level) corr-softmax stats ----------------
__global__ __launch_bounds__(256) void stats_kernel(const float* __restrict__ c0,
                                                    const float* __restrict__ c1,
                                                    const float* __restrict__ c2,
                                                    const float* __restrict__ c3,
                                                    const float* __restrict__ vr,
                                                    float* __restrict__ stats) {
  const int LS[4] = {92, 46, 23, 12};
  const int LHW[4] = {8464, 2116, 529, 144};
  int b = blockIdx.x >> 2, l = blockIdx.x & 3;
  const float* cp = (l == 0) ? c0 : (l == 1) ? c1 : (l == 2) ? c2 : c3;
  int S = LS[l], HW = LHW[l];
  float vrx = vr[(b * 4 + l) * 2 + 0], vry = vr[(b * 4 + l) * 2 + 1];
  int tid = threadIdx.x;
  __shared__ float red[4];

  float mx = -INFINITY;
  for (int i = tid; i < HW; i += 256) {
    float c = cp[(size_t)b * HW + i];
    if (c >= 0.5f) mx = fmaxf(mx, c);
  }
  for (int o = 32; o; o >>= 1) mx = fmaxf(mx, __shfl_xor(mx, o));
  if ((tid & 63) == 0) red[tid >> 6] = mx;
  __syncthreads();
  mx = fmaxf(fmaxf(red[0], red[1]), fmaxf(red[2], red[3]));
  float mx_eff = isinf(mx) ? 0.f : mx;
  __syncthreads();

  float den = 0.f, cx = 0.f, cy = 0.f;
  float invW = 1.f / (vrx * (float)S), invH = 1.f / (vry * (float)S);
  for (int i = tid; i < HW; i += 256) {
    float c = cp[(size_t)b * HW + i];
    if (c >= 0.5f) {
      float e = expf(c - mx_eff);
      int x = i % S, y = i / S;
      den += e;
      cx += e * ((float)x + 0.5f) * invW;
      cy += e * ((float)y + 0.5f) * invH;
    }
  }
  float vals[3] = {den, cx, cy};
  for (int j = 0; j < 3; ++j) {
    float v = vals[j];
    for (int o = 32; o; o >>= 1) v += __shfl_xor(v, o);
    if ((tid & 63) == 0) red[tid >> 6] = v;
    __syncthreads();
    v = red[0] + red[1] + red[2] + red[3];
    vals[j] = v;
    __syncthreads();
  }
  if (tid == 0) {
    float* s = stats + (size_t)(b * 4 + l) * 4;
    s[0] = mx_eff; s[1] = vals[0]; s[2] = vals[1]; s[3] = vals[2];
  }
}

// ---------------- reference points + corr_all ----------------
__global__ __launch_bounds__(256) void refpt_kernel(const float* __restrict__ c0,
                                                    const float* __restrict__ c1,
                                                    const float* __restrict__ c2,
                                                    const float* __restrict__ c3,
                                                    const float* __restrict__ vr,
                                                    const float* __restrict__ stats,
                                                    float* __restrict__ refpt,
                                                    float* __restrict__ corr_all) {
  int i = blockIdx.x * 256 + threadIdx.x;
  if (i >= MT) return;
  int b = i / NTOT, n = i % NTOT;
  int l = (n < 8464) ? 0 : (n < 10580) ? 1 : (n < 11109) ? 2 : 3;
  const int LS[4] = {92, 46, 23, 12};
  const int LSTART[4] = {0, 8464, 10580, 11109};
  const int LHW[4] = {8464, 2116, 529, 144};
  int S = LS[l], start = LSTART[l], HW = LHW[l];
  int local = n - start;
  int x = local % S, y = local / S;
  float vrx = vr[(b * 4 + l) * 2 + 0], vry = vr[(b * 4 + l) * 2 + 1];
  float rx = ((float)x + 0.5f) / (vrx * (float)S);
  float ry = ((float)y + 0.5f) / (vry * (float)S);
  const float* cp = (l == 0) ? c0 : (l == 1) ? c1 : (l == 2) ? c2 : c3;
  float c = cp[(size_t)b * HW + local];
  const float* st = stats + (size_t)(b * 4 + l) * 4;
  float mx = st[0], den = st[1], cxs = st[2], cys = st[3];
  float sm = 0.f, cenx = 0.f, ceny = 0.f;
  if (den > 0.f) {
    if (c >= 0.5f) sm = expf(c - mx) / fmaxf(den, 1e-30f);
    cenx = cxs / den; ceny = cys / den;
  }
  float dx = fminf(fmaxf(cenx - rx, -0.5f), 0.5f) * sm;
  float dy = fminf(fmaxf(ceny - ry, -0.5f), 0.5f) * sm;
  refpt[2 * i] = rx + dx;
  refpt[2 * i + 1] = ry + dy;
  corr_all[i] = c;
}

// ======= 8-wave GEMM core: 256x128 tile, BK=64, single-buffer, XOR swizzle (512 thr) =======
#define GEMM_CORE8(A_, Bt_, K_)                                                        \
  const int tid = threadIdx.x;                                                         \
  const int wid = tid >> 6, lane = tid & 63;                                           \
  const int row0 = blockIdx.x * 256;                                                   \
  const int wm = wid >> 1, wn = wid & 1;                                               \
  const int l15 = lane & 15;                                                           \
  const int hi = lane >> 4;                                                            \
  const int s7 = l15 & 7;                                                              \
  __shared__ __align__(16) unsigned short Als[256][64];                                \
  __shared__ __align__(16) unsigned short Bls[128][64];                                \
  f32x4 acc[4][4];                                                                     \
  const f32x4 zero = {0.f, 0.f, 0.f, 0.f};                                             \
  _Pragma("unroll") for (int a = 0; a < 4; ++a)                                        \
    _Pragma("unroll") for (int c = 0; c < 4; ++c) acc[a][c] = zero;                    \
  const unsigned short* gA[4];                                                         \
  const unsigned short* gB[2];                                                         \
  unsigned short* lA[4];                                                               \
  unsigned short* lB[2];                                                               \
  _Pragma("unroll") for (int j = 0; j < 4; ++j) {                                      \
    int cch = tid + 512 * j;                                                           \
    int rrow = cch >> 3;                                                               \
    int gseg = (cch & 7) ^ (rrow & 7);                                                 \
    int ra = row0 + rrow; if (ra > MT - 1) ra = MT - 1;                                \
    gA[j] = A_ + (size_t)ra * K_ + gseg * 8;                                           \
    lA[j] = &Als[0][0] + (size_t)cch * 8;                                              \
  }                                                                                    \
  _Pragma("unroll") for (int j = 0; j < 2; ++j) {                                      \
    int cch = tid + 512 * j;                                                           \
    int rrow = cch >> 3;                                                               \
    int gseg = (cch & 7) ^ (rrow & 7);                                                 \
    gB[j] = Bt_ + (size_t)(col0 + rrow) * K_ + gseg * 8;                               \
    lB[j] = &Bls[0][0] + (size_t)cch * 8;                                              \
  }                                                                                    \
  for (int k0 = 0; k0 < K_; k0 += 64) {                                                \
    __syncthreads();                                                                   \
    _Pragma("unroll") for (int j = 0; j < 4; ++j) gld16(gA[j] + k0, lA[j]);            \
    _Pragma("unroll") for (int j = 0; j < 2; ++j) gld16(gB[j] + k0, lB[j]);            \
    __syncthreads();                                                                   \
    _Pragma("unroll") for (int ks = 0; ks < 2; ++ks) {                                 \
      bf16x8 av[4], bv[4];                                                             \
      const int m = ks * 4 + hi;                                                       \
      _Pragma("unroll") for (int f = 0; f < 4; ++f) {                                  \
        av[f] = *(const bf16x8*)&Als[wm * 64 + f * 16 + l15][(m ^ s7) * 8];            \
        bv[f] = *(const bf16x8*)&Bls[wn * 64 + f * 16 + l15][(m ^ s7) * 8];            \
      }                                                                                \
      _Pragma("unroll") for (int fm = 0; fm < 4; ++fm)                                 \
        _Pragma("unroll") for (int fn = 0; fn < 4; ++fn)                               \
          acc[fm][fn] = __builtin_amdgcn_mfma_f32_16x16x32_bf16(av[fm], bv[fn], acc[fm][fn], 0, 0, 0); \
    }                                                                                  \
  }

// ---------------- gemmS8: bf16 relu out (FFN1) ----------------
__global__ __launch_bounds__(512, 4) void gemmS8(const unsigned short* __restrict__ A,
                                                 const unsigned short* __restrict__ Bt,
                                                 const float* __restrict__ bias,
                                                 unsigned short* __restrict__ out,
                                                 int K, int N) {
  const int col0 = blockIdx.y * 128;
  GEMM_CORE8(A, Bt, K)
#pragma unroll
  for (int fm = 0; fm < 4; ++fm) {
#pragma unroll
    for (int fn = 0; fn < 4; ++fn) {
      int gcol = col0 + wn * 64 + fn * 16 + l15;
      float bcol = bias[gcol];
#pragma unroll
      for (int r = 0; r < 4; ++r) {
        int grow = row0 + wm * 64 + fm * 16 + hi * 4 + r;
        if (grow < MT) {
          float v = acc[fm][fn][r] + bcol;
          out[(size_t)grow * N + gcol] = f2bf(fmaxf(v, 0.f));
        }
      }
    }
  }
}

// ---------------- merged value + offsets/logits GEMM (8-wave, both K=256, bf16 out) ----------------
__global__ __launch_bounds__(512, 4) void gemm_voa(const unsigned short* __restrict__ Av,
                                                   const unsigned short* __restrict__ Aoa,
                                                   const unsigned short* __restrict__ Btv,
                                                   const unsigned short* __restrict__ Btoa,
                                                   const float* __restrict__ bv,
                                                   const float* __restrict__ boa,
                                                   const float* __restrict__ c_oa,
                                                   const float* __restrict__ corr,
                                                   unsigned short* __restrict__ outv,
                                                   unsigned short* __restrict__ outo,
                                                   unsigned short* __restrict__ outl) {
  const bool isV = blockIdx.y < 2;
  const int col0 = (isV ? blockIdx.y : blockIdx.y - 2) * 128;
  const unsigned short* A = isV ? Av : Aoa;
  const unsigned short* Bt = isV ? Btv : Btoa;
  const float* bias = isV ? bv : boa;
  GEMM_CORE8(A, Bt, 256)
#pragma unroll
  for (int fm = 0; fm < 4; ++fm) {
#pragma unroll
    for (int fn = 0; fn < 4; ++fn) {
      int gcol = col0 + wn * 64 + fn * 16 + l15;
      float bcol = bias[gcol];
      float cv = isV ? 0.f : c_oa[gcol];
#pragma unroll
      for (int r = 0; r < 4; ++r) {
        int grow = row0 + wm * 64 + fm * 16 + hi * 4 + r;
        if (grow < MT) {
          float v = acc[fm][fn][r] + bcol;
          if (isV) {
            outv[(size_t)grow * 256 + gcol] = f2bf(v);
          } else {
            v += corr[grow] * cv;
            if (gcol < 256) outo[(size_t)grow * 256 + gcol] = f2bf(v);
            else outl[(size_t)grow * 128 + gcol - 256] = f2bf(v);
          }
        }
      }
    }
  }
}

// ---------------- fused GEMM + bf16 residual + LayerNorm: 64x256 tile (full rows) ----------------
template <int OUTF32>
__global__ __launch_bounds__(256, 3) void gemm_ln(const unsigned short* __restrict__ A,
                                                  const unsigned short* __restrict__ Bt,
                                                  const float* __restrict__ bias,
                                                  const unsigned short* __restrict__ residbf,
                                                  const float* __restrict__ lng,
                                                  const float* __restrict__ lnb,
                                                  void* __restrict__ out,
                                                  int K) {
  const int tid = threadIdx.x;
  const int w = tid >> 6, lane = tid & 63;
  const int row0 = blockIdx.x * 64;
  const int l15 = lane & 15;
  const int hi = lane >> 4;
  const int s7 = l15 & 7;

  __shared__ __align__(16) unsigned short Als[64][64];
  __shared__ __align__(16) unsigned short Bls[256][64];

  f32x4 acc[16];
  const f32x4 zero = {0.f, 0.f, 0.f, 0.f};
#pragma unroll
  for (int cf = 0; cf < 16; ++cf) acc[cf] = zero;

  const unsigned short* gA[2];
  unsigned short* lA[2];
#pragma unroll
  for (int j = 0; j < 2; ++j) {
    int c = tid + 256 * j;
    int rrow = c >> 3;
    int gseg = (c & 7) ^ (rrow & 7);
    int ra = row0 + rrow; if (ra > MT - 1) ra = MT - 1;
    gA[j] = A + (size_t)ra * K + gseg * 8;
    lA[j] = &Als[0][0] + (size_t)c * 8;
  }
  const unsigned short* gB[8];
  unsigned short* lB[8];
#pragma unroll
  for (int j = 0; j < 8; ++j) {
    int c = tid + 256 * j;
    int rrow = c >> 3;
    int gseg = (c & 7) ^ (rrow & 7);
    gB[j] = Bt + (size_t)rrow * K + gseg * 8;
    lB[j] = &Bls[0][0] + (size_t)c * 8;
  }

  for (int k0 = 0; k0 < K; k0 += 64) {
    __syncthreads();
#pragma unroll
    for (int j = 0; j < 2; ++j) gld16(gA[j] + k0, lA[j]);
#pragma unroll
    for (int j = 0; j < 8; ++j) gld16(gB[j] + k0, lB[j]);
    __syncthreads();
#pragma unroll
    for (int ks = 0; ks < 2; ++ks) {
      const int m = ks * 4 + hi;
      bf16x8 av = *(const bf16x8*)&Als[w * 16 + l15][(m ^ s7) * 8];
#pragma unroll
      for (int cf = 0; cf < 16; ++cf) {
        bf16x8 bvv = *(const bf16x8*)&Bls[cf * 16 + l15][(m ^ s7) * 8];
        acc[cf] = __builtin_amdgcn_mfma_f32_16x16x32_bf16(av, bvv, acc[cf], 0, 0, 0);
      }
    }
  }

#pragma unroll
  for (int r = 0; r < 4; ++r) {
    int grow = row0 + w * 16 + hi * 4 + r;
    bool valid = grow < MT;
    float vals[16];
    float s = 0.f;
#pragma unroll
    for (int cf = 0; cf < 16; ++cf) {
      int gcol = cf * 16 + l15;
      float v = acc[cf][r] + bias[gcol];
      if (valid) v += bf2f(residbf[(size_t)grow * 256 + gcol]);
      vals[cf] = v;
      s += v;
    }
    for (int o = 1; o < 16; o <<= 1) s += __shfl_xor(s, o);
    float mean = s * (1.f / 256.f);
    float q = 0.f;
#pragma unroll
    for (int cf = 0; cf < 16; ++cf) {
      float d = vals[cf] - mean;
      q += d * d;
    }
    for (int o = 1; o < 16; o <<= 1) q += __shfl_xor(q, o);
    float rstd = rsqrtf(q * (1.f / 256.f) + 1e-5f);
    if (valid) {
#pragma unroll
      for (int cf = 0; cf < 16; ++cf) {
        int gcol = cf * 16 + l15;
        float o = (vals[cf] - mean) * rstd * lng[gcol] + lnb[gcol];
        if constexpr (OUTF32) {
          ((float*)out)[(size_t)grow * 256 + gcol] = o;
        } else {
          ((unsigned short*)out)[(size_t)grow * 256 + gcol] = f2bf(o);
        }
      }
    }
  }
}

// ---------------- deformable sampling (R14-validated: bf16 value/offs/logits, fused softmax) ----------------
__global__ __launch_bounds__(256) void sampler2_kernel(const unsigned short* __restrict__ value,
                                                       const unsigned* __restrict__ offs_bf,
                                                       const unsigned short* __restrict__ logits_bf,
                                                       const float* __restrict__ refpt,
                                                       const float* __restrict__ vr,
                                                       unsigned short* __restrict__ outs) {
  const int LS[4] = {92, 46, 23, 12};
  const int LSTART[4] = {0, 8464, 10580, 11109};
  const int tid = threadIdx.x;
  const int rsel = tid >> 7;
  const int r = blockIdx.x * 2 + rsel;

  __shared__ __align__(16) int4 s_addr[2][8][17];
  __shared__ __align__(16) float4 s_w[2][8][17];

  {
    int pt = tid & 127;
    int l = (pt >> 2) & 3;
    int h = pt >> 4;
    int b = r / NTOT;
    unsigned op = offs_bf[(size_t)r * 128 + pt];
    float ox = __uint_as_float(op << 16);
    float oy = __uint_as_float(op & 0xFFFF0000u);
    float lg = bf2f(logits_bf[(size_t)r * 128 + pt]);
    float m = lg;
    for (int o = 1; o < 16; o <<= 1) m = fmaxf(m, __shfl_xor(m, o));
    float e = expf(lg - m);
    float s = e;
    for (int o = 1; o < 16; o <<= 1) s += __shfl_xor(s, o);
    float aw = e / s;

    float rx = refpt[2 * r], ry = refpt[2 * r + 1];
    float vrx = vr[(b * 4 + l) * 2 + 0], vry = vr[(b * 4 + l) * 2 + 1];
    int S = LS[l];
    float fS = (float)S;
    float xf = rx * vrx * fS + ox - 0.5f;
    float yf = ry * vry * fS + oy - 0.5f;
    float x0f = floorf(xf), y0f = floorf(yf);
    float wx = xf - x0f, wy = yf - y0f;
    int x0 = (int)x0f, y0 = (int)y0f;
    int x1 = x0 + 1, y1 = y0 + 1;
    float vx0 = ((unsigned)x0 < (unsigned)S) ? 1.f : 0.f;
    float vx1 = ((unsigned)x1 < (unsigned)S) ? 1.f : 0.f;
    float vy0 = ((unsigned)y0 < (unsigned)S) ? 1.f : 0.f;
    float vy1 = ((unsigned)y1 < (unsigned)S) ? 1.f : 0.f;
    int cx0 = min(max(x0, 0), S - 1), cx1 = min(max(x1, 0), S - 1);
    int cy0 = min(max(y0, 0), S - 1), cy1 = min(max(y1, 0), S - 1);
    int base = (b * NTOT + LSTART[l]) * 512 + h * 64;
    int4 a;
    a.x = base + (cy0 * S + cx0) * 512;
    a.y = base + (cy0 * S + cx1) * 512;
    a.z = base + (cy1 * S + cx0) * 512;
    a.w = base + (cy1 * S + cx1) * 512;
    float iwx = 1.f - wx, iwy = 1.f - wy;
    float4 w;
    w.x = aw * iwx * iwy * vx0 * vy0;
    w.y = aw * wx * iwy * vx1 * vy0;
    w.z = aw * iwx * wy * vx0 * vy1;
    w.w = aw * wx * wy * vx1 * vy1;
    s_addr[rsel][h][pt & 15] = a;
    s_w[rsel][h][pt & 15] = w;
  }
  __syncthreads();

  const int h = (tid >> 4) & 7, cp = tid & 15;
  const char* vb = (const char*)value;
  const int cpo = cp * 4;
  float a0 = 0.f, a1 = 0.f;
#pragma unroll 4
  for (int i = 0; i < 16; ++i) {
    int4 a = s_addr[rsel][h][i];
    float4 w = s_w[rsel][h][i];
    unsigned u00 = *(const unsigned*)(vb + (size_t)(unsigned)(a.x + cpo));
    unsigned u01 = *(const unsigned*)(vb + (size_t)(unsigned)(a.y + cpo));
    unsigned u10 = *(const unsigned*)(vb + (size_t)(unsigned)(a.z + cpo));
    unsigned u11 = *(const unsigned*)(vb + (size_t)(unsigned)(a.w + cpo));
    float f00l = __uint_as_float(u00 << 16), f00h = __uint_as_float(u00 & 0xFFFF0000u);
    float f01l = __uint_as_float(u01 << 16), f01h = __uint_as_float(u01 & 0xFFFF0000u);
    float f10l = __uint_as_float(u10 << 16), f10h = __uint_as_float(u10 & 0xFFFF0000u);
    float f11l = __uint_as_float(u11 << 16), f11h = __uint_as_float(u11 & 0xFFFF0000u);
    a0 += w.x * f00l + w.y * f01l + w.z * f10l + w.w * f11l;
    a1 += w.x * f00h + w.y * f01h + w.z * f10h + w.w * f11h;
  }
  unsigned packed = (unsigned)f2bf(a0) | ((unsigned)f2bf(a1) << 16);
  ((unsigned*)outs)[(size_t)r * 128 + h * 16 + cp] = packed;
}

// ---------------- launch ----------------
extern "C" void kernel_launch(void* const* d_in, const int* in_sizes, int n_in,
                              void* d_out, int out_size, void* d_ws, size_t ws_size,
                              hipStream_t stream) {
  (void)in_sizes; (void)n_in; (void)out_size; (void)ws_size;
  const float* src = (const float*)d_in[0];
  const float* pos = (const float*)d_in[1];
  const float* c0 = (const float*)d_in[2];
  const float* c1 = (const float*)d_in[3];
  const float* c2 = (const float*)d_in[4];
  const float* c3 = (const float*)d_in[5];
  const float* vr = (const float*)d_in[6];
  const float* W_off = (const float*)d_in[8];
  const float* b_off = (const float*)d_in[9];
  const float* W_attn = (const float*)d_in[10];
  const float* b_attn = (const float*)d_in[11];
  const float* W_val = (const float*)d_in[12];
  const float* b_val = (const float*)d_in[13];
  const float* W_out = (const float*)d_in[14];
  const float* b_out = (const float*)d_in[15];
  const float* ln1g = (const float*)d_in[16];
  const float* ln1b = (const float*)d_in[17];
  const float* W1 = (const float*)d_in[18];
  const float* b1 = (const float*)d_in[19];
  const float* W2 = (const float*)d_in[20];
  const float* b2 = (const float*)d_in[21];
  const float* ln2g = (const float*)d_in[22];
  const float* ln2b = (const float*)d_in[23];

  char* ws = (char*)d_ws;
  // S1 (46MB): value_bf16 (23MB)
  unsigned short* value_bf = (unsigned short*)(ws + 0);
  // S2 (46MB): offs_bf (23MB, then x_bf16 overwrites) + logits_bf (11.5MB)
  unsigned* offs_bf = (unsigned*)(ws + 46092288);
  unsigned short* x_bf16 = (unsigned short*)(ws + 46092288);
  unsigned short* logits_bf = (unsigned short*)(ws + 69138432);
  // S4 (23MB): src_bf16 (persists through outproj as residual)
  unsigned short* src_bf16 = (unsigned short*)(ws + 92184576);
  // region C (92MB): qa (front 23MB) -> out_s -> hbuf spans all
  unsigned short* qa = (unsigned short*)(ws + 115230720);
  unsigned short* out_s = qa;
  unsigned short* hbuf = (unsigned short*)(ws + 115230720);
  // small region
  unsigned short* Wt_val = (unsigned short*)(ws + 207415296);
  unsigned short* Wt_oa = (unsigned short*)(ws + 207546368);
  unsigned short* Wt_out = (unsigned short*)(ws + 207742976);
  unsigned short* Wt1 = (unsigned short*)(ws + 207874048);
  unsigned short* Wt2 = (unsigned short*)(ws + 208398336);
  float* c_oa = (float*)(ws + 208922624);
  float* refpt = (float*)(ws + 208924160);
  float* corr_all = (float*)(ws + 209284256);
  float* stats = (float*)(ws + 209464304);
  float* b_oa = (float*)(ws + 209465344);

  prep_kernel<<<2946, 256, 0, stream>>>(W_val, W_off, W_attn, W_out, W1, W2, b_off, b_attn,
                                        Wt_val, Wt_oa, Wt_out, Wt1, Wt2, c_oa, b_oa);

  cvt_kernel<<<11253, 256, 0, stream>>>((const float4*)src, (const float4*)pos,
                                        (ushort4*)src_bf16, (ushort4*)qa);
  stats_kernel<<<16, 256, 0, stream>>>(c0, c1, c2, c3, vr, stats);
  refpt_kernel<<<176, 256, 0, stream>>>(c0, c1, c2, c3, vr, stats, refpt, corr_all);

  // merged: value bf16 (y<2) + offsets/logits bf16 (y>=2); 8-wave 256x128 blocks
  gemm_voa<<<dim3(176, 5), dim3(512), 0, stream>>>(src_bf16, qa, Wt_val, Wt_oa, b_val, b_oa,
                                                   c_oa, corr_all, value_bf,
                                                   (unsigned short*)offs_bf, logits_bf);
  // deformable sampling -> out_s (bf16, in qa slot; src_bf16 preserved)
  sampler2_kernel<<<MT / 2, 256, 0, stream>>>(value_bf, offs_bf, logits_bf, refpt, vr, out_s);
  // fused outproj + resid(src) + LN1 -> x_bf16 (overwrites offs_bf, dead)
  gemm_ln<0><<<704, 256, 0, stream>>>(out_s, Wt_out, b_out, src_bf16, ln1g, ln1b, x_bf16, 256);
  // FFN1: h = bf16(relu(x @ W1 + b1)); 8-wave 256x128 blocks
  gemmS8<<<dim3(176, 8), dim3(512), 0, stream>>>(x_bf16, Wt1, b1, hbuf, 256, 1024);
  // fused FFN2 + resid(x) + LN2 -> d_out (f32)
  gemm_ln<1><<<704, 256, 0, stream>>>(hbuf, Wt2, b2, x_bf16, ln2g, ln2b, d_out, 1024);
}